// Round 14
// baseline (200.788 us; speedup 1.0000x reference)
//
#include <hip/hip_runtime.h>

// Problem constants: B=32, D=64, H=W=32 -> N=32768 rows; K=1024 codes
#define OUT_OFF_Q 0          // quantized (straight-through fwd) [B,D,H,W]
#define OUT_OFF_VQ 2097152   // scalar vq_loss
#define OUT_OFF_PPL 2097153  // scalar perplexity
#define OUT_OFF_ENC 2097154  // encoded one-hot [N, K]

typedef __attribute__((ext_vector_type(8))) short short8;   // 8 bf16 (4 VGPRs)
typedef __attribute__((ext_vector_type(4))) float f32x4;    // MFMA C/D

__device__ __forceinline__ unsigned short f2bf(float f) {   // RNE f32->bf16
    unsigned u = __builtin_bit_cast(unsigned, f);
    u += 0x7fffu + ((u >> 16) & 1u);
    return (unsigned short)(u >> 16);
}
__device__ __forceinline__ float bf2f(unsigned short h) {
    unsigned u = ((unsigned)h) << 16;
    return __builtin_bit_cast(float, u);
}

// ---------------------------------------------------------------------------
// prepfill: (a) all 1024 blocks zero-fill a 128KB slice of the one-hot
// output (99.997% of encoded bytes, no dependencies); (b) blocks 0..63 build
// the packed bf16 hi/lo A-fragment stream + ee[k]; block 64 zeroes counters.
// Efrag layout: [kt(64)][j(4)][lane(64)] x 16B -> main k-loop fragment loads
// are perfectly coalesced.
__global__ __launch_bounds__(256) void vq_prepfill(
    const float* __restrict__ E, unsigned short* __restrict__ Efrag,
    float* __restrict__ ee, int* __restrict__ counts,
    float* __restrict__ lossSum, unsigned int* __restrict__ doneCnt,
    float* __restrict__ out)
{
    const int t = threadIdx.x;
    const int bk = blockIdx.x;

    // --- fragment prep: blocks 0..63, first wave (t<64) ---
    if (bk < 64 && t < 64) {
        const int kt = bk;
        const int code = kt * 16 + (t & 15);
        const int q = t >> 4;
        const float* ep0 = E + code * 64 + q * 8;        // d = q*8 .. q*8+7
        const float* ep1 = ep0 + 32;                     // d = 32+q*8 ..
        short8 ah0, ah1, al0, al1;
        float s = 0.f;
        #pragma unroll
        for (int j = 0; j < 8; ++j) {
            float v0 = ep0[j];
            unsigned short h0 = f2bf(v0);
            ah0[j] = (short)h0;
            al0[j] = (short)f2bf(v0 - bf2f(h0));
            s = fmaf(v0, v0, s);
            float v1 = ep1[j];
            unsigned short h1 = f2bf(v1);
            ah1[j] = (short)h1;
            al1[j] = (short)f2bf(v1 - bf2f(h1));
            s = fmaf(v1, v1, s);
        }
        short8* dst = (short8*)Efrag + (size_t)kt * 256;
        dst[0 * 64 + t] = ah0;
        dst[1 * 64 + t] = ah1;
        dst[2 * 64 + t] = al0;
        dst[3 * 64 + t] = al1;
        s += __shfl_xor(s, 16);
        s += __shfl_xor(s, 32);
        if (t < 16) ee[code] = s;
    }
    if (bk == 64) {
        #pragma unroll
        for (int i = 0; i < 4; ++i) counts[t * 4 + i] = 0;
        if (t == 0) { lossSum[0] = 0.f; *doneCnt = 0u; }
    }

    // --- zero-fill: every block clears 8192 f32x4 (32 one-hot rows) ---
    f32x4* enc = (f32x4*)(out + OUT_OFF_ENC) + (size_t)bk * 8192;
    const f32x4 z = {0.f, 0.f, 0.f, 0.f};
    #pragma unroll
    for (int i = 0; i < 32; ++i)
        enc[i * 256 + t] = z;        // coalesced full-line stores
}

// ---------------------------------------------------------------------------
// main (2-launch version): 1024 blocks x 256 threads. Block owns 32
// consecutive n; wave w owns codes [w*256,(w+1)*256), register-dbuf coalesced
// fragment loads. Writes: quantized (8MB), one 1.0f dword per row, counts +
// loss via DEVICE-SCOPE ATOMICS (no __threadfence — R7 lesson: fences after
// big dirty streams are catastrophic; here the per-block dirty set is ~10KB
// and communication is atomics-only). Last block computes the scalars.
__global__ __launch_bounds__(256, 4) void vq_main(
    const float* __restrict__ X, const float* __restrict__ E,
    const unsigned short* __restrict__ Efrag, const float* __restrict__ ee,
    float* __restrict__ out, int* __restrict__ counts,
    float* __restrict__ lossSum, unsigned int* __restrict__ doneCnt)
{
    __shared__ float s_val[4][32];
    __shared__ int   s_idx[4][32];
    __shared__ float s_loss[4];
    __shared__ float s_red[4];
    __shared__ int   s_last;

    const int t = threadIdx.x;
    const int l = t & 63;
    const int w = __builtin_amdgcn_readfirstlane(t >> 6);
    const int col = l & 15;
    const int quad = l >> 4;
    const int n0 = blockIdx.x * 32;
    const int b = n0 >> 10;
    const int hwb = n0 & 1023;

    // B-fragments (x): B[d][n]: n = col + 16*nt, d = ks*32 + quad*8 + j
    short8 bh[2][2], bl[2][2];
    const float* xb = X + (size_t)b * 65536 + hwb;
    #pragma unroll
    for (int nt = 0; nt < 2; ++nt) {
        const float* xn = xb + nt * 16 + col;
        #pragma unroll
        for (int ks = 0; ks < 2; ++ks) {
            short8 vh, vl;
            #pragma unroll
            for (int j = 0; j < 8; ++j) {
                float v = xn[(size_t)(ks * 32 + quad * 8 + j) * 1024];
                unsigned short hb = f2bf(v);
                vh[j] = (short)hb;
                vl[j] = (short)f2bf(v - bf2f(hb));
            }
            bh[nt][ks] = vh;
            bl[nt][ks] = vl;
        }
    }

    // --- k-loop over this wave's 16 tiles; register double-buffer ---
    float best[2] = {3.4e38f, 3.4e38f};
    int   bidx[2] = {0, 0};
    const short8* fw = (const short8*)Efrag + (size_t)(w * 16) * 256;
    short8 ah0 = fw[0 * 64 + l];
    short8 ah1 = fw[1 * 64 + l];
    short8 al0 = fw[2 * 64 + l];
    short8 al1 = fw[3 * 64 + l];
    for (int kt = 0; kt < 16; ++kt) {
        const short8* fb = fw + (size_t)((kt + 1) & 15) * 256;  // prefetch
        short8 ph0 = fb[0 * 64 + l];
        short8 ph1 = fb[1 * 64 + l];
        short8 pl0 = fb[2 * 64 + l];
        short8 pl1 = fb[3 * 64 + l];

        const int kb = w * 256 + kt * 16;
        f32x4 eev = *((const f32x4*)(ee + kb + quad * 4));   // L1-hot
        #pragma unroll
        for (int nt = 0; nt < 2; ++nt) {
            f32x4 c = {0.f, 0.f, 0.f, 0.f};
            c = __builtin_amdgcn_mfma_f32_16x16x32_bf16(ah0, bh[nt][0], c, 0, 0, 0);
            c = __builtin_amdgcn_mfma_f32_16x16x32_bf16(ah1, bh[nt][1], c, 0, 0, 0);
            c = __builtin_amdgcn_mfma_f32_16x16x32_bf16(al0, bh[nt][0], c, 0, 0, 0);
            c = __builtin_amdgcn_mfma_f32_16x16x32_bf16(al1, bh[nt][1], c, 0, 0, 0);
            c = __builtin_amdgcn_mfma_f32_16x16x32_bf16(ah0, bl[nt][0], c, 0, 0, 0);
            c = __builtin_amdgcn_mfma_f32_16x16x32_bf16(ah1, bl[nt][1], c, 0, 0, 0);
            // C/D: col = lane&15 (n), row = quad*4 + r (k within tile)
            #pragma unroll
            for (int r = 0; r < 4; ++r) {
                float val = fmaf(-2.f, c[r], eev[r]);
                int k = kb + quad * 4 + r;
                if (val < best[nt]) { best[nt] = val; bidx[nt] = k; }
            }
        }
        ah0 = ph0; ah1 = ph1; al0 = pl0; al1 = pl1;
    }

    // reduce across quads (lanes l, l^16, l^32, l^48 share (nt,col))
    #pragma unroll
    for (int nt = 0; nt < 2; ++nt) {
        float v = best[nt]; int i = bidx[nt];
        float ov = __shfl_xor(v, 16); int oi = __shfl_xor(i, 16);
        if (ov < v || (ov == v && oi < i)) { v = ov; i = oi; }
        ov = __shfl_xor(v, 32); oi = __shfl_xor(i, 32);
        if (ov < v || (ov == v && oi < i)) { v = ov; i = oi; }
        best[nt] = v; bidx[nt] = i;
    }
    if (quad < 2) {
        s_val[w][quad * 16 + col] = best[quad];
        s_idx[w][quad * 16 + col] = bidx[quad];
    }
    __syncthreads();

    // cross-wave reduce; publish idx, counts, and the one-hot 1.0 dword
    if (t < 32) {
        float fv = s_val[0][t]; int fi0 = s_idx[0][t];
        #pragma unroll
        for (int j = 1; j < 4; ++j) {
            float v = s_val[j][t]; int i = s_idx[j][t];
            if (v < fv || (v == fv && i < fi0)) { fv = v; fi0 = i; }
        }
        s_idx[0][t] = fi0;
        atomicAdd(&counts[fi0], 1);            // device-scope, coherent
        out[OUT_OFF_ENC + ((size_t)(n0 + t) << 10) + fi0] = 1.0f;
    }
    __syncthreads();

    // quantized store + loss: wave w handles d in [16w,16w+16) for 32 n.
    {
        const int nl = l & 31;
        const int half = l >> 5;
        const int fi = s_idx[0][nl];
        const int hw = hwb + nl;
        const int d0 = (w << 4) + (half << 3);
        const float* er = E + ((size_t)fi << 6) + d0;
        float4 g0 = *(const float4*)(er);
        float4 g1 = *(const float4*)(er + 4);
        float q[8] = {g0.x, g0.y, g0.z, g0.w, g1.x, g1.y, g1.z, g1.w};
        float* op = out + OUT_OFF_Q + (size_t)b * 65536 + hw;
        const float* xp = X + (size_t)b * 65536 + hw;
        float lsum = 0.f;
        #pragma unroll
        for (int dd = 0; dd < 8; ++dd) {
            const int d = d0 + dd;
            op[(size_t)d * 1024] = q[dd];           // regular coalesced store
            float diff = q[dd] - xp[(size_t)d * 1024];
            lsum = fmaf(diff, diff, lsum);
        }
        #pragma unroll
        for (int off = 32; off; off >>= 1) lsum += __shfl_down(lsum, off);
        if (l == 0) s_loss[w] = lsum;
    }
    __syncthreads();

    // --- last-block finalize via atomics-only handshake (no threadfence) ---
    if (t == 0) {
        float blockLoss = s_loss[0] + s_loss[1] + s_loss[2] + s_loss[3];
        atomicAdd(lossSum, blockLoss);         // device-scope, coherent
        unsigned prev = __hip_atomic_fetch_add(doneCnt, 1u, __ATOMIC_ACQ_REL,
                                               __HIP_MEMORY_SCOPE_AGENT);
        s_last = (prev == 1023u);
    }
    __syncthreads();
    if (s_last) {
        float pv = 0.f;
        for (int i = t; i < 1024; i += 256) {
            int c = __hip_atomic_load(&counts[i], __ATOMIC_RELAXED,
                                      __HIP_MEMORY_SCOPE_AGENT);
            float p = (float)c * (1.0f / 32768.0f);
            pv += p * logf(p + 1e-10f);
        }
        #pragma unroll
        for (int off = 32; off; off >>= 1) pv += __shfl_down(pv, off);
        if (l == 0) s_red[w] = pv;
        __syncthreads();
        if (t == 0) {
            float sp = s_red[0] + s_red[1] + s_red[2] + s_red[3];
            float sl = __hip_atomic_load(lossSum, __ATOMIC_RELAXED,
                                         __HIP_MEMORY_SCOPE_AGENT);
            out[OUT_OFF_PPL] = expf(-sp);
            out[OUT_OFF_VQ] = 1.25f * sl * (1.0f / 2097152.0f);
        }
    }
}

extern "C" void kernel_launch(void* const* d_in, const int* in_sizes, int n_in,
                              void* d_out, int out_size, void* d_ws, size_t ws_size,
                              hipStream_t stream) {
    const float* X = (const float*)d_in[0];   // [32, 64, 32, 32] fp32
    const float* E = (const float*)d_in[1];   // [1024, 64] fp32
    float* out = (float*)d_out;

    // ws layout
    int* counts = (int*)d_ws;                                      // 4 KiB
    float* lossSum = (float*)((char*)d_ws + 4096);                 // 4 B
    unsigned int* doneCnt = (unsigned int*)((char*)d_ws + 8192);   // 4 B
    float* ee = (float*)((char*)d_ws + 12288);                     // 4 KiB
    unsigned short* Efrag = (unsigned short*)((char*)d_ws + 16384);// 256 KiB

    vq_prepfill<<<1024, 256, 0, stream>>>(E, Efrag, ee, counts, lossSum,
                                          doneCnt, out);
    vq_main<<<1024, 256, 0, stream>>>(X, E, Efrag, ee, out, counts,
                                      lossSum, doneCnt);
}

// Round 15
// 168.003 us; speedup vs baseline: 1.1951x; 1.1951x over previous
//
#include <hip/hip_runtime.h>

// Problem constants: B=32, D=64, H=W=32 -> N=32768 rows; K=1024 codes
#define OUT_OFF_Q 0          // quantized (straight-through fwd) [B,D,H,W]
#define OUT_OFF_VQ 2097152   // scalar vq_loss
#define OUT_OFF_PPL 2097153  // scalar perplexity
#define OUT_OFF_ENC 2097154  // encoded one-hot [N, K]

typedef __attribute__((ext_vector_type(8))) short short8;   // 8 bf16 (4 VGPRs)
typedef __attribute__((ext_vector_type(4))) float f32x4;    // MFMA C/D

__device__ __forceinline__ unsigned short f2bf(float f) {   // RNE f32->bf16
    unsigned u = __builtin_bit_cast(unsigned, f);
    u += 0x7fffu + ((u >> 16) & 1u);
    return (unsigned short)(u >> 16);
}
__device__ __forceinline__ float bf2f(unsigned short h) {
    unsigned u = ((unsigned)h) << 16;
    return __builtin_bit_cast(float, u);
}

// ---------------------------------------------------------------------------
// prep: build packed bf16 hi/lo A-fragment stream + ee[k] + zero counts.
// Efrag layout: [kt(64)][j(4)][lane(64)] x 16B, so the main k-loop's 4
// fragment loads are each perfectly coalesced (64 lanes x 16B contiguous).
__global__ __launch_bounds__(64) void vq_prep(
    const float* __restrict__ E, unsigned short* __restrict__ Efrag,
    float* __restrict__ ee, int* __restrict__ counts)
{
    const int t = threadIdx.x;
    const int kt = blockIdx.x;
    const int code = kt * 16 + (t & 15);
    const int q = t >> 4;

    const float* ep0 = E + code * 64 + q * 8;        // d = q*8 .. q*8+7
    const float* ep1 = ep0 + 32;                     // d = 32+q*8 ..
    short8 ah0, ah1, al0, al1;
    float s = 0.f;
    #pragma unroll
    for (int j = 0; j < 8; ++j) {
        float v0 = ep0[j];
        unsigned short h0 = f2bf(v0);
        ah0[j] = (short)h0;
        al0[j] = (short)f2bf(v0 - bf2f(h0));
        s = fmaf(v0, v0, s);
        float v1 = ep1[j];
        unsigned short h1 = f2bf(v1);
        ah1[j] = (short)h1;
        al1[j] = (short)f2bf(v1 - bf2f(h1));
        s = fmaf(v1, v1, s);
    }
    short8* dst = (short8*)Efrag + (size_t)kt * 256;  // 4 frag-planes x 64 lanes
    dst[0 * 64 + t] = ah0;
    dst[1 * 64 + t] = ah1;
    dst[2 * 64 + t] = al0;
    dst[3 * 64 + t] = al1;

    // ||e||^2: reduce partial s across the 4 quads sharing this code
    s += __shfl_xor(s, 16);
    s += __shfl_xor(s, 32);
    if (t < 16) ee[code] = s;

    // zero counts (4096 threads total, need 1024)
    const int gid = blockIdx.x * 64 + t;
    if (gid < 1024) counts[gid] = 0;
}

// ---------------------------------------------------------------------------
// main (final, R12 config — best of 6 structural probes): 1024 blocks x 256
// threads. Block owns 32 consecutive n; wave w owns codes [w*256,(w+1)*256)
// = tiles w*16..+15, register double-buffered coalesced fragment loads, eev
// straight from global (L1-hot). Fused epilogue: quantized store + loss
// partial + one-hot encode with regular write-back stores.
// Session lessons baked in:
//  - R5/R6: pack E into a [kt][frag][lane] stream so every k-loop load is a
//    coalesced dwordx4 (divergent A-frag gathers were the 90us stall).
//  - R9: regular stores, NOT nontemporal (NT ~40% slower for full-line
//    streams on gfx950).
//  - R7/R14: never fuse a grid-wide finalize (fence or atomic handshake)
//    into a kernel with a large dirty write stream.
//  - R10/R11/R13: 32-n blocks + per-wave 256-code split + fused fill is the
//    optimum; wave-independent, 64-n, and split-fill variants all regress.
__global__ __launch_bounds__(256, 4) void vq_main(
    const float* __restrict__ X, const float* __restrict__ E,
    const unsigned short* __restrict__ Efrag, const float* __restrict__ ee,
    float* __restrict__ out, int* __restrict__ counts,
    float* __restrict__ lossPart)
{
    __shared__ float s_val[4][32];
    __shared__ int   s_idx[4][32];
    __shared__ float s_loss[4];

    const int t = threadIdx.x;
    const int l = t & 63;
    const int w = __builtin_amdgcn_readfirstlane(t >> 6);
    const int col = l & 15;
    const int quad = l >> 4;
    const int n0 = blockIdx.x * 32;
    const int b = n0 >> 10;
    const int hwb = n0 & 1023;

    // B-fragments (x): B[d][n]: n = col + 16*nt, d = ks*32 + quad*8 + j
    short8 bh[2][2], bl[2][2];
    const float* xb = X + (size_t)b * 65536 + hwb;
    #pragma unroll
    for (int nt = 0; nt < 2; ++nt) {
        const float* xn = xb + nt * 16 + col;
        #pragma unroll
        for (int ks = 0; ks < 2; ++ks) {
            short8 vh, vl;
            #pragma unroll
            for (int j = 0; j < 8; ++j) {
                float v = xn[(size_t)(ks * 32 + quad * 8 + j) * 1024];
                unsigned short hb = f2bf(v);
                vh[j] = (short)hb;
                vl[j] = (short)f2bf(v - bf2f(hb));
            }
            bh[nt][ks] = vh;
            bl[nt][ks] = vl;
        }
    }

    // --- k-loop over this wave's 16 tiles; register double-buffer ---
    float best[2] = {3.4e38f, 3.4e38f};
    int   bidx[2] = {0, 0};
    const short8* fw = (const short8*)Efrag + (size_t)(w * 16) * 256;
    short8 ah0 = fw[0 * 64 + l];     // tile 0 fragments
    short8 ah1 = fw[1 * 64 + l];
    short8 al0 = fw[2 * 64 + l];
    short8 al1 = fw[3 * 64 + l];
    for (int kt = 0; kt < 16; ++kt) {
        const short8* fb = fw + (size_t)((kt + 1) & 15) * 256;  // prefetch
        short8 ph0 = fb[0 * 64 + l];
        short8 ph1 = fb[1 * 64 + l];
        short8 pl0 = fb[2 * 64 + l];
        short8 pl1 = fb[3 * 64 + l];

        const int kb = w * 256 + kt * 16;
        f32x4 eev = *((const f32x4*)(ee + kb + quad * 4));   // L1-hot
        #pragma unroll
        for (int nt = 0; nt < 2; ++nt) {
            f32x4 c = {0.f, 0.f, 0.f, 0.f};
            c = __builtin_amdgcn_mfma_f32_16x16x32_bf16(ah0, bh[nt][0], c, 0, 0, 0);
            c = __builtin_amdgcn_mfma_f32_16x16x32_bf16(ah1, bh[nt][1], c, 0, 0, 0);
            c = __builtin_amdgcn_mfma_f32_16x16x32_bf16(al0, bh[nt][0], c, 0, 0, 0);
            c = __builtin_amdgcn_mfma_f32_16x16x32_bf16(al1, bh[nt][1], c, 0, 0, 0);
            c = __builtin_amdgcn_mfma_f32_16x16x32_bf16(ah0, bl[nt][0], c, 0, 0, 0);
            c = __builtin_amdgcn_mfma_f32_16x16x32_bf16(ah1, bl[nt][1], c, 0, 0, 0);
            // C/D: col = lane&15 (n), row = quad*4 + r (k within tile)
            #pragma unroll
            for (int r = 0; r < 4; ++r) {
                float val = fmaf(-2.f, c[r], eev[r]);
                int k = kb + quad * 4 + r;
                if (val < best[nt]) { best[nt] = val; bidx[nt] = k; }
            }
        }
        ah0 = ph0; ah1 = ph1; al0 = pl0; al1 = pl1;
    }

    // reduce across quads (lanes l, l^16, l^32, l^48 share (nt,col))
    #pragma unroll
    for (int nt = 0; nt < 2; ++nt) {
        float v = best[nt]; int i = bidx[nt];
        float ov = __shfl_xor(v, 16); int oi = __shfl_xor(i, 16);
        if (ov < v || (ov == v && oi < i)) { v = ov; i = oi; }
        ov = __shfl_xor(v, 32); oi = __shfl_xor(i, 32);
        if (ov < v || (ov == v && oi < i)) { v = ov; i = oi; }
        best[nt] = v; bidx[nt] = i;
    }
    if (quad < 2) {
        s_val[w][quad * 16 + col] = best[quad];
        s_idx[w][quad * 16 + col] = bidx[quad];
    }
    __syncthreads();

    // cross-wave reduce, publish idx + counts
    if (t < 32) {
        float fv = s_val[0][t]; int fi0 = s_idx[0][t];
        #pragma unroll
        for (int j = 1; j < 4; ++j) {
            float v = s_val[j][t]; int i = s_idx[j][t];
            if (v < fv || (v == fv && i < fi0)) { fv = v; fi0 = i; }
        }
        s_idx[0][t] = fi0;
        atomicAdd(&counts[fi0], 1);
    }
    __syncthreads();

    // quantized store + loss: wave w handles d in [16w,16w+16) for 32 n.
    {
        const int nl = l & 31;
        const int half = l >> 5;
        const int fi = s_idx[0][nl];
        const int hw = hwb + nl;
        const int d0 = (w << 4) + (half << 3);
        const float* er = E + ((size_t)fi << 6) + d0;
        float4 g0 = *(const float4*)(er);
        float4 g1 = *(const float4*)(er + 4);
        float q[8] = {g0.x, g0.y, g0.z, g0.w, g1.x, g1.y, g1.z, g1.w};
        float* op = out + OUT_OFF_Q + (size_t)b * 65536 + hw;
        const float* xp = X + (size_t)b * 65536 + hw;
        float lsum = 0.f;
        #pragma unroll
        for (int dd = 0; dd < 8; ++dd) {
            const int d = d0 + dd;
            op[(size_t)d * 1024] = q[dd];           // regular coalesced store
            float diff = q[dd] - xp[(size_t)d * 1024];
            lsum = fmaf(diff, diff, lsum);
        }
        #pragma unroll
        for (int off = 32; off; off >>= 1) lsum += __shfl_down(lsum, off);
        if (l == 0) s_loss[w] = lsum;
    }
    __syncthreads();
    if (t == 0)
        lossPart[blockIdx.x] = s_loss[0] + s_loss[1] + s_loss[2] + s_loss[3];

    // fused one-hot encode: wave w writes rows [8w, 8w+8), regular f32x4
    // stores (1 KB contiguous per wave-instruction = 16 full 64B lines)
    {
        f32x4* enc = (f32x4*)(out + OUT_OFF_ENC);
        const int rbase = w << 3;
        for (int rr = 0; rr < 8; ++rr) {
            const int r = rbase + rr;
            const int ridx = s_idx[0][r];
            f32x4* erow = enc + (size_t)(n0 + r) * 256;
            #pragma unroll
            for (int c4 = 0; c4 < 4; ++c4) {
                const int kb4 = (c4 << 8) + (l << 2);
                f32x4 v = {0.f, 0.f, 0.f, 0.f};
                const int dlt = ridx - kb4;
                if (dlt == 0) v.x = 1.f;
                else if (dlt == 1) v.y = 1.f;
                else if (dlt == 2) v.z = 1.f;
                else if (dlt == 3) v.w = 1.f;
                erow[(c4 << 6) + l] = v;            // regular store
            }
        }
    }
}

// ---------------------------------------------------------------------------
__global__ __launch_bounds__(1024) void vq_finalize(
    const int* __restrict__ counts, const float* __restrict__ lossPart,
    float* __restrict__ out)
{
    __shared__ float redp[16];
    __shared__ float redl[16];
    const int t = threadIdx.x;
    const float p = (float)counts[t] * (1.0f / 32768.0f);
    float v = p * logf(p + 1e-10f);
    float ls = lossPart[t];
    #pragma unroll
    for (int off = 32; off; off >>= 1) {
        v += __shfl_down(v, off);
        ls += __shfl_down(ls, off);
    }
    if ((t & 63) == 0) { redp[t >> 6] = v; redl[t >> 6] = ls; }
    __syncthreads();
    if (t == 0) {
        float s = 0.f, sl = 0.f;
        #pragma unroll
        for (int i = 0; i < 16; ++i) { s += redp[i]; sl += redl[i]; }
        out[OUT_OFF_PPL] = expf(-s);
        out[OUT_OFF_VQ] = 1.25f * sl * (1.0f / 2097152.0f);
    }
}

extern "C" void kernel_launch(void* const* d_in, const int* in_sizes, int n_in,
                              void* d_out, int out_size, void* d_ws, size_t ws_size,
                              hipStream_t stream) {
    const float* X = (const float*)d_in[0];   // [32, 64, 32, 32] fp32
    const float* E = (const float*)d_in[1];   // [1024, 64] fp32
    float* out = (float*)d_out;

    // ws layout
    int* counts = (int*)d_ws;                                      // 4 KiB
    float* lossPart = (float*)((char*)d_ws + 4096);                // 4 KiB
    float* ee = (float*)((char*)d_ws + 8192);                      // 4 KiB
    unsigned short* Efrag = (unsigned short*)((char*)d_ws + 12288);// 256 KiB

    vq_prep<<<64, 64, 0, stream>>>(E, Efrag, ee, counts);
    vq_main<<<1024, 256, 0, stream>>>(X, E, Efrag, ee, out, counts, lossPart);
    vq_finalize<<<1, 1024, 0, stream>>>(counts, lossPart, out);
}